// Round 1
// baseline (184.708 us; speedup 1.0000x reference)
//
#include <hip/hip_runtime.h>
#include <math.h>

// Problem dims (fixed by reference)
#define BATCH 32
#define CH    1024     // C == P
#define NPix  784      // H*W = 28*28
#define MMOD  4        // M models, Q == 1
#define NPC   16       // p-chunks in k_norm_z
#define PPC   64       // channels per chunk (NPC*PPC == CH)
#define T2    832      // 13 waves: covers 784 pixels (+48 idle lanes)

__device__ __forceinline__ float wave_reduce(float s) {
    #pragma unroll
    for (int off = 32; off; off >>= 1) s += __shfl_down(s, off, 64);
    return s;
}

// Kernel 1: per (b, p-chunk) block: compute channel norms (phase A), then
// accumulate partial z[b,m,n] over this chunk's 64 channels (phase B).
// Phase B re-reads the same 200KB the block just streamed -> L2 hit.
__global__ __launch_bounds__(T2) void k_norm_z(const float* __restrict__ x,
                                               const float* __restrict__ Wm,
                                               float* __restrict__ inv_norm,
                                               float* __restrict__ zpart) {
    __shared__ float inv_lds[PPC];
    __shared__ float wlds[MMOD][PPC];
    const int blk = blockIdx.x;
    const int b  = blk >> 4;        // /NPC
    const int pc = blk & (NPC - 1);
    const int t = threadIdx.x;
    const int wv = t >> 6, lane = t & 63;
    const float* xb = x + ((size_t)b * CH + (size_t)pc * PPC) * NPix;

    // ---- phase A: L2 norms of the 64 rows owned by this block ----
    for (int row = wv; row < PPC; row += 13) {
        const float4* r4 = (const float4*)(xb + (size_t)row * NPix); // 196 float4
        float s = 0.f;
        #pragma unroll
        for (int i = 0; i < 3; i++) {
            float4 v = r4[i * 64 + lane];
            s += v.x*v.x + v.y*v.y + v.z*v.z + v.w*v.w;
        }
        if (lane < 4) {
            float4 v = r4[192 + lane];
            s += v.x*v.x + v.y*v.y + v.z*v.z + v.w*v.w;
        }
        s = wave_reduce(s);
        if (lane == 0) {
            float inv = 1.f / fmaxf(sqrtf(s), 1e-10f);
            inv_lds[row] = inv;
            inv_norm[b * CH + pc * PPC + row] = inv;
        }
    }
    __syncthreads();

    // ---- build w'[m][p] = Wm[m,p] * inv_norm[b,p] in LDS ----
    if (t < PPC) {
        float inv = inv_lds[t];
        #pragma unroll
        for (int m = 0; m < MMOD; m++)
            wlds[m][t] = Wm[m * CH + pc * PPC + t] * inv;
    }
    __syncthreads();

    // ---- phase B: z partial over this chunk's channels; thread t owns pixel n=t ----
    if (t < NPix) {
        float a0 = 0.f, a1 = 0.f, a2 = 0.f, a3 = 0.f;
        const float* xp = xb + t;
        #pragma unroll 8
        for (int pp = 0; pp < PPC; pp++) {
            float xv = xp[(size_t)pp * NPix];   // coalesced across threads
            a0 += wlds[0][pp] * xv;
            a1 += wlds[1][pp] * xv;
            a2 += wlds[2][pp] * xv;
            a3 += wlds[3][pp] * xv;
        }
        size_t base = (((size_t)b * NPC + pc) * MMOD) * NPix + t;
        zpart[base]            = a0;
        zpart[base + NPix]     = a1;
        zpart[base + 2 * NPix] = a2;
        zpart[base + 3 * NPix] = a3;
    }
}

// Kernel 2: one block per b. Reduce zpart over chunks, sigmoid, s2 = sum g^2
// per m (block reduction), then h[b,n] = sum_m g[m,n]/s2[m].
__global__ __launch_bounds__(T2) void k_gh(const float* __restrict__ zpart,
                                           float* __restrict__ h) {
    __shared__ float red[13][MMOD];
    __shared__ float s2s[MMOD];
    const int b = blockIdx.x;
    const int t = threadIdx.x;
    const int wv = t >> 6, lane = t & 63;
    const bool act = (t < NPix);

    float g[MMOD];
    #pragma unroll
    for (int m = 0; m < MMOD; m++) {
        float z = 0.f;
        if (act) {
            #pragma unroll
            for (int pc = 0; pc < NPC; pc++)
                z += zpart[(((size_t)b * NPC + pc) * MMOD + m) * NPix + t];
        }
        g[m] = act ? 1.f / (1.f + expf(-z)) : 0.f;
    }
    #pragma unroll
    for (int m = 0; m < MMOD; m++) {
        float s = wave_reduce(g[m] * g[m]);
        if (lane == 0) red[wv][m] = s;
    }
    __syncthreads();
    if (t < MMOD) {
        float s = 0.f;
        #pragma unroll
        for (int w = 0; w < 13; w++) s += red[w][t];
        s2s[t] = fmaxf(s, 1e-30f);
    }
    __syncthreads();
    if (act) {
        float hv = 0.f;
        #pragma unroll
        for (int m = 0; m < MMOD; m++) hv += g[m] / s2s[m];
        h[(size_t)b * NPix + t] = hv;
    }
}

// Kernel 3: out[b,p] = inv_norm[b,p] * dot(x[b,p,:], h[b,:]).
// One wave per (b,p) row; 4 rows per 256-thread block (all same b: 4 | 1024).
__global__ __launch_bounds__(256) void k_out(const float* __restrict__ x,
                                             const float* __restrict__ h,
                                             const float* __restrict__ inv_norm,
                                             float* __restrict__ out) {
    const int r = blockIdx.x * 4 + (threadIdx.x >> 6);  // r in [0, 32768)
    const int lane = threadIdx.x & 63;
    const int b = r >> 10;
    const float4* x4 = (const float4*)(x + (size_t)r * NPix);
    const float4* h4 = (const float4*)(h + (size_t)b * NPix);
    float s = 0.f;
    #pragma unroll
    for (int i = 0; i < 3; i++) {
        float4 xv = x4[i * 64 + lane];
        float4 hv = h4[i * 64 + lane];
        s += xv.x*hv.x + xv.y*hv.y + xv.z*hv.z + xv.w*hv.w;
    }
    if (lane < 4) {
        float4 xv = x4[192 + lane];
        float4 hv = h4[192 + lane];
        s += xv.x*hv.x + xv.y*hv.y + xv.z*hv.z + xv.w*hv.w;
    }
    s = wave_reduce(s);
    if (lane == 0) {
        float v = s * inv_norm[r];
        // nan_to_num semantics: nan->0, +/-inf -> +/-FLT_MAX
        if (!(v == v)) v = 0.f;
        v = fminf(fmaxf(v, -3.402823466e+38f), 3.402823466e+38f);
        out[r] = v;
    }
}

extern "C" void kernel_launch(void* const* d_in, const int* in_sizes, int n_in,
                              void* d_out, int out_size, void* d_ws, size_t ws_size,
                              hipStream_t stream) {
    const float* x  = (const float*)d_in[0];   // [32,1024,28,28]
    const float* Wm = (const float*)d_in[1];   // [4,1,1024]
    float* out = (float*)d_out;                // [32,1024]
    float* wsf = (float*)d_ws;

    float* inv_norm = wsf;                                    // 32768 floats
    float* zpart    = inv_norm + BATCH * CH;                  // 32*16*4*784 = 1605632 floats
    float* h        = zpart + (size_t)BATCH * NPC * MMOD * NPix; // 25088 floats

    k_norm_z<<<BATCH * NPC, T2, 0, stream>>>(x, Wm, inv_norm, zpart);
    k_gh<<<BATCH, T2, 0, stream>>>(zpart, h);
    k_out<<<BATCH * CH / 4, 256, 0, stream>>>(x, h, inv_norm, out);
}